// Round 8
// baseline (169.101 us; speedup 1.0000x reference)
//
#include <hip/hip_runtime.h>

// Cubic B-spline interpolation (SplineInter), 2D, m=1024x1024, PAD=2.
// Grid: coeffs (1028 x 1028) float32, flat-clamped gather per reference.
//
// R1: row-vectorized gathers (4x dwordx4/point): 48 us kernel.
// R2: MLP probe: no change -> scattered-gather THROUGHPUT bound (~3.7 cyc
//     per 64B line per CU), not latency-bound.
// R3-R5: sort-based pipelines all lose: the permutation itself costs one
//     full scattered stream + extra passes. NT scattered stores: disaster.
// R6: fat fp16 grid (1 line/pt, 32 MB): neutral. Footprint blew L2 (4 MB/
//     XCD) -> each lookup became an L3 random line (~12 cyc vs 3.7 L2).
//     Lookup-count and footprint trade off; storage axis exhausted.
// R7: hypothesis = the 3.7 cyc/line is L1 line ALLOCATION cost (every line
//     used exactly once -> allocation is pure overhead). Probe: nontemporal
//     (nt) loads on the 4 row gathers to bypass L1 fill, stream from the
//     L2-resident compact grid. Structure otherwise identical to R2.

#define I1 1028
#define TOTAL (1028 * 1028)

typedef float f4u __attribute__((ext_vector_type(4), aligned(4)));

__device__ __forceinline__ void basis4(float t, float w[4]) {
    float a = 1.0f - t;
    w[0] = a * a * a;                                // j=-1: (1-t)^3
    w[1] = (3.0f * t - 6.0f) * (t * t) + 4.0f;       // j=0
    float xi = t - 1.0f;
    w[2] = -(3.0f * xi + 6.0f) * (xi * xi) + 4.0f;   // j=1
    w[3] = t * t * t;                                // j=2
}

__device__ __forceinline__ void point_cell(float2 xy, int& P0, int& P1,
                                           float& t0, float& t1, bool& valid) {
    float xn0 = xy.x * 1024.0f - 0.5f;
    float xn1 = xy.y * 1024.0f - 0.5f;
    valid = (xn0 > -2.0f) && (xn0 < 1024.0f) &&
            (xn1 > -2.0f) && (xn1 < 1024.0f);
    float P0f = floorf(xn0);
    float P1f = floorf(xn1);
    P0 = (int)P0f;
    P1 = (int)P1f;
    t0 = xn0 - P0f;
    t1 = xn1 - P1f;
}

// Exact reference semantics: flat-clamped scalar gather (always correct).
__device__ __forceinline__ float eval_slow(const float* __restrict__ coeffs,
                                           int base, const float w0[4],
                                           const float w1[4]) {
    float acc = 0.0f;
#pragma unroll
    for (int j = 0; j < 4; ++j) {
        int r = base + (j - 1) * I1 - 1;
        float s = 0.0f;
#pragma unroll
        for (int k = 0; k < 4; ++k) {
            int idx = min(max(r + k, 0), TOTAL - 1);
            s = fmaf(coeffs[idx], w1[k], s);
        }
        acc = fmaf(s, w0[j], acc);
    }
    return acc;
}

__global__ __launch_bounds__(256) void spline_interp_nt_kernel(
    const float* __restrict__ x,      // [N,2] interleaved
    const float* __restrict__ coeffs, // [1028*1028]
    float* __restrict__ out,          // [N]
    int n)
{
    int i = blockIdx.x * blockDim.x + threadIdx.x;
    if (i >= n) return;

    float2 xy = reinterpret_cast<const float2*>(x)[i];
    int P0, P1; float t0, t1; bool valid;
    point_cell(xy, P0, P1, t0, t1, valid);

    float w0[4], w1[4];
    basis4(t0, w0);
    basis4(t1, w1);

    int base = I1 * (2 + P0) + (2 + P1);
    // Stencil spans [base - I1 - 1, base + 2*I1 + 2]; fully in range =>
    // the element-wise flat clamp can never fire.
    bool interior = (base - I1 - 1 >= 0) && (base + 2 * I1 + 2 <= TOTAL - 1);

    float acc = 0.0f;
    if (interior) {
#pragma unroll
        for (int j = 0; j < 4; ++j) {
            const f4u* rp = reinterpret_cast<const f4u*>(coeffs + base + (j - 1) * I1 - 1);
            f4u v = __builtin_nontemporal_load(rp);   // nt: no L1 allocation
            float s = fmaf(v.x, w1[0],
                      fmaf(v.y, w1[1],
                      fmaf(v.z, w1[2],
                           v.w * w1[3])));
            acc = fmaf(s, w0[j], acc);
        }
    } else {
        acc = eval_slow(coeffs, base, w0, w1);
    }

    out[i] = valid ? acc : 0.0f;
}

extern "C" void kernel_launch(void* const* d_in, const int* in_sizes, int n_in,
                              void* d_out, int out_size, void* d_ws, size_t ws_size,
                              hipStream_t stream) {
    const float* x = (const float*)d_in[0];       // [N,2]
    const float* coeffs = (const float*)d_in[1];  // [1028*1028]
    float* out = (float*)d_out;                   // [N]

    int n = in_sizes[0] / 2;  // number of points (2,097,152)
    int block = 256;
    int grid = (n + block - 1) / block;
    spline_interp_nt_kernel<<<grid, block, 0, stream>>>(x, coeffs, out, n);
}